// Round 1
// baseline (328.593 us; speedup 1.0000x reference)
//
#include <hip/hip_runtime.h>
#include <hip/hip_bf16.h>

// VeRA: out = SCALE * d_B[o] * ((x @ (d_A*A)^T) @ B^T)
// GEMM1 (split-K=4): part[s] = x @ Ab^T over K-chunk  (M=8192,N=256,K=1024 each)
// reduce: t = bf16(sum_s part[s])
// GEMM2: out = SCALE*d_B * (t @ Bb^T)  (M=8192,N=4096,K=256)
//
// This revision: T2 XOR-swizzled LDS (kills the 16-way bank conflict that was
// ~43% of gemm1 cycles) + T3-minimum 2-phase double-buffered pipeline in both
// GEMMs. gemm1 stages x as bf16 via reg-staging (cvt once, not per-fragment).

#define SCALE_F 0.125f
#define M_TOT 8192
#define K_IN 4096
#define RANK 256
#define N_OUT 4096
#define S_SPLIT 4
#define KC 1024   // K_IN / S_SPLIT

typedef __bf16 bf16_t;
typedef __bf16 bf16x8 __attribute__((ext_vector_type(8)));
typedef __bf16 bf16x4 __attribute__((ext_vector_type(4)));
typedef float f32x4 __attribute__((ext_vector_type(4)));

typedef __attribute__((address_space(3))) unsigned int lds_u32_t;
typedef const __attribute__((address_space(1))) unsigned int glob_u32_t;

__device__ __forceinline__ void async16(const void* g, void* l) {
    __builtin_amdgcn_global_load_lds((glob_u32_t*)g, (lds_u32_t*)l, 16, 0, 0);
}

// ---- convert A (fold d_A) and B to bf16 ----
__global__ __launch_bounds__(256) void conv_A(const float* __restrict__ A,
                                              const float* __restrict__ dA,
                                              bf16_t* __restrict__ Ab) {
    int idx = blockIdx.x * 256 + threadIdx.x;
    float4 v = ((const float4*)A)[idx];
    float s = dA[idx >> 10];
    bf16x4 o;
    o.x = (bf16_t)(v.x * s); o.y = (bf16_t)(v.y * s);
    o.z = (bf16_t)(v.z * s); o.w = (bf16_t)(v.w * s);
    ((bf16x4*)Ab)[idx] = o;
}

__global__ __launch_bounds__(256) void conv_B(const float* __restrict__ B,
                                              bf16_t* __restrict__ Bb) {
    int idx = blockIdx.x * 256 + threadIdx.x;
    float4 v = ((const float4*)B)[idx];
    bf16x4 o;
    o.x = (bf16_t)v.x; o.y = (bf16_t)v.y; o.z = (bf16_t)v.z; o.w = (bf16_t)v.w;
    ((bf16x4*)Bb)[idx] = o;
}

// ---- GEMM1: part[z][8192][256] = x(fp32) @ Ab^T over K-chunk z ----
// BM=64, BN=128, BK=64. grid (128, 2, 4). 4 waves 2x2, wave tile 32x64.
// LDS swizzle: 16B slot s of row r lives at slot s^(r&7) (both arrays have
// 8-slot rows). sA is staged via global_load_lds -> LDS dest stays LINEAR,
// the global SOURCE slot is pre-swizzled (same cachelines -> coalescing kept).
// sX is reg-staged (f32->bf16 cvt once) -> ds_write directly to swizzled slot.
__global__ __launch_bounds__(256) void gemm1(const float* __restrict__ x,
                                             const bf16_t* __restrict__ Ab,
                                             bf16_t* __restrict__ part) {
    __shared__ bf16_t sX[2][64 * 64];    // 8 KB per buffer (bf16 now)
    __shared__ bf16_t sA[2][128 * 64];   // 16 KB per buffer; total 48 KB -> 3 blocks/CU
    const int tid = threadIdx.x;
    const int lane = tid & 63, wave = tid >> 6;
    const int wm = wave >> 1, wn = wave & 1;
    const int l15 = lane & 15, quad = lane >> 4;
    const int bm = blockIdx.x * 64;
    const int bn = blockIdx.y * 128;
    const int k0 = blockIdx.z * KC;

    f32x4 acc[2][4];
    const f32x4 zero = {0.f, 0.f, 0.f, 0.f};
    #pragma unroll
    for (int i = 0; i < 2; i++)
        #pragma unroll
        for (int j = 0; j < 4; j++) acc[i][j] = zero;

    f32x4 xr[2][2];   // in-flight x tile (2 chunks x 8 f32 per thread)

    auto issue_x = [&](int kk) {   // issue global loads early; consumed in write_x
        #pragma unroll
        for (int c = 0; c < 2; c++) {
            int idx = c * 256 + tid;
            int row = idx >> 3, sl = idx & 7;
            const float* sp = &x[(size_t)(bm + row) * K_IN + kk + sl * 8];
            xr[c][0] = *(const f32x4*)sp;
            xr[c][1] = *(const f32x4*)(sp + 4);
        }
    };
    auto stage_a = [&](int b, int kk) {   // async16: linear LDS dest, swizzled src
        #pragma unroll
        for (int c = 0; c < 4; c++) {
            int idx = c * 256 + tid;
            int row = idx >> 3, sl = idx & 7;
            async16(&Ab[(size_t)(bn + row) * K_IN + kk + ((sl ^ (row & 7)) << 3)],
                    &sA[b][idx * 8]);
        }
    };
    auto write_x = [&](int b) {   // cvt + ds_write to swizzled slot
        #pragma unroll
        for (int c = 0; c < 2; c++) {
            int idx = c * 256 + tid;
            int row = idx >> 3, sl = idx & 7;
            bf16x8 o;
            #pragma unroll
            for (int e = 0; e < 4; e++) {
                o[e]     = (bf16_t)xr[c][0][e];
                o[e + 4] = (bf16_t)xr[c][1][e];
            }
            *(bf16x8*)&sX[b][row * 64 + ((sl ^ (row & 7)) << 3)] = o;
        }
    };
    auto compute = [&](int b) {
        #pragma unroll
        for (int ks = 0; ks < 2; ks++) {
            bf16x8 af[2], bfr[4];
            #pragma unroll
            for (int i = 0; i < 2; i++) {
                int row = wm * 32 + i * 16 + l15;
                af[i] = *(const bf16x8*)&sX[b][row * 64 + ((((ks << 2) | quad) ^ (row & 7)) << 3)];
            }
            #pragma unroll
            for (int j = 0; j < 4; j++) {
                int row = wn * 64 + j * 16 + l15;
                bfr[j] = *(const bf16x8*)&sA[b][row * 64 + ((((ks << 2) | quad) ^ (row & 7)) << 3)];
            }
            #pragma unroll
            for (int i = 0; i < 2; i++)
                #pragma unroll
                for (int j = 0; j < 4; j++)
                    acc[i][j] = __builtin_amdgcn_mfma_f32_16x16x32_bf16(af[i], bfr[j], acc[i][j], 0, 0, 0);
        }
    };

    // prologue: fill buffer 0
    issue_x(k0);
    stage_a(0, k0);
    write_x(0);
    __syncthreads();

    // 2-phase main loop: prefetch(nxt) || compute(cur); one barrier per K-step
    int cur = 0;
    for (int it = 1; it < KC / 64; ++it) {
        const int nxt = cur ^ 1;
        const int kk = k0 + it * 64;
        issue_x(kk);          // global->reg, latency hides under compute
        stage_a(nxt, kk);     // global->LDS DMA, latency hides under compute
        compute(cur);
        write_x(nxt);         // waits vmcnt for xr, then ds_write
        __syncthreads();      // drains async16 + ds ops
        cur = nxt;
    }
    compute(cur);

    bf16_t* p = part + (size_t)blockIdx.z * (M_TOT * RANK);
    #pragma unroll
    for (int i = 0; i < 2; i++) {
        #pragma unroll
        for (int j = 0; j < 4; j++) {
            int col = bn + wn * 64 + j * 16 + l15;
            #pragma unroll
            for (int r = 0; r < 4; r++) {
                int row = bm + wm * 32 + i * 16 + quad * 4 + r;
                p[(size_t)row * RANK + col] = (bf16_t)acc[i][j][r];
            }
        }
    }
}

// ---- reduce: t = bf16(sum_z part[z]) ----
__global__ __launch_bounds__(256) void reduce_t(const bf16_t* __restrict__ part,
                                                bf16_t* __restrict__ t) {
    int i = (blockIdx.x * 256 + threadIdx.x) * 8;
    float s[8] = {0.f, 0.f, 0.f, 0.f, 0.f, 0.f, 0.f, 0.f};
    #pragma unroll
    for (int z = 0; z < S_SPLIT; z++) {
        bf16x8 v = *(const bf16x8*)&part[(size_t)z * M_TOT * RANK + i];
        #pragma unroll
        for (int e = 0; e < 8; e++) s[e] += (float)v[e];
    }
    bf16x8 o;
    #pragma unroll
    for (int e = 0; e < 8; e++) o[e] = (bf16_t)s[e];
    *(bf16x8*)&t[i] = o;
}

// ---- GEMM2: out[8192][4096] = SCALE*dB * (t @ Bb^T) ----
// BM=128, BN=128, BK=64. grid (64,32)=2048 blocks. 4 waves 2x2, wave tile 64x64.
// Same swizzle + 2-phase dbuf as gemm1; both operands via async16 with
// pre-swizzled global source. LDS 64 KB -> 2 blocks/CU.
__global__ __launch_bounds__(256) void gemm2(const bf16_t* __restrict__ t,
                                             const bf16_t* __restrict__ Bb,
                                             const float* __restrict__ dB,
                                             float* __restrict__ out) {
    __shared__ bf16_t sT[2][128 * 64];   // 16 KB each
    __shared__ bf16_t sB[2][128 * 64];   // 16 KB each
    const int tid = threadIdx.x;
    const int lane = tid & 63, wave = tid >> 6;
    const int wm = wave >> 1, wn = wave & 1;
    const int l15 = lane & 15, quad = lane >> 4;
    const int bm = blockIdx.x * 128;
    const int bn = blockIdx.y * 128;

    f32x4 acc[4][4];
    const f32x4 zero = {0.f, 0.f, 0.f, 0.f};
    #pragma unroll
    for (int i = 0; i < 4; i++)
        #pragma unroll
        for (int j = 0; j < 4; j++) acc[i][j] = zero;

    auto stage = [&](int b, int kt) {
        #pragma unroll
        for (int c = 0; c < 4; c++) {
            int idx = c * 256 + tid;
            int row = idx >> 3, sl = idx & 7;
            async16(&t[(size_t)(bm + row) * RANK + kt + ((sl ^ (row & 7)) << 3)],
                    &sT[b][idx * 8]);
        }
        #pragma unroll
        for (int c = 0; c < 4; c++) {
            int idx = c * 256 + tid;
            int row = idx >> 3, sl = idx & 7;
            async16(&Bb[(size_t)(bn + row) * RANK + kt + ((sl ^ (row & 7)) << 3)],
                    &sB[b][idx * 8]);
        }
    };
    auto compute = [&](int b) {
        #pragma unroll
        for (int ks = 0; ks < 2; ks++) {
            bf16x8 af[4], bfr[4];
            #pragma unroll
            for (int i = 0; i < 4; i++) {
                int row = wm * 64 + i * 16 + l15;
                af[i] = *(const bf16x8*)&sT[b][row * 64 + ((((ks << 2) | quad) ^ (row & 7)) << 3)];
            }
            #pragma unroll
            for (int j = 0; j < 4; j++) {
                int row = wn * 64 + j * 16 + l15;
                bfr[j] = *(const bf16x8*)&sB[b][row * 64 + ((((ks << 2) | quad) ^ (row & 7)) << 3)];
            }
            #pragma unroll
            for (int i = 0; i < 4; i++)
                #pragma unroll
                for (int j = 0; j < 4; j++)
                    acc[i][j] = __builtin_amdgcn_mfma_f32_16x16x32_bf16(af[i], bfr[j], acc[i][j], 0, 0, 0);
        }
    };

    stage(0, 0);
    __syncthreads();
    int cur = 0;
    #pragma unroll
    for (int it = 1; it < RANK / 64; ++it) {
        stage(cur ^ 1, it * 64);
        compute(cur);
        __syncthreads();
        cur ^= 1;
    }
    compute(cur);

    #pragma unroll
    for (int j = 0; j < 4; j++) {
        int col = bn + wn * 64 + j * 16 + l15;
        float db = dB[col] * SCALE_F;
        #pragma unroll
        for (int i = 0; i < 4; i++) {
            #pragma unroll
            for (int r = 0; r < 4; r++) {
                int row = bm + wm * 64 + i * 16 + quad * 4 + r;
                out[(size_t)row * N_OUT + col] = db * acc[i][j][r];
            }
        }
    }
}

extern "C" void kernel_launch(void* const* d_in, const int* in_sizes, int n_in,
                              void* d_out, int out_size, void* d_ws, size_t ws_size,
                              hipStream_t stream) {
    const float* x  = (const float*)d_in[0];
    const float* A  = (const float*)d_in[1];
    const float* B  = (const float*)d_in[2];
    const float* dA = (const float*)d_in[3];
    const float* dB = (const float*)d_in[4];
    float* out = (float*)d_out;

    char* ws = (char*)d_ws;
    bf16_t* Ab   = (bf16_t*)ws;                       // 2 MB
    bf16_t* Bb   = (bf16_t*)(ws + (1u << 21));        // 2 MB
    bf16_t* tt   = (bf16_t*)(ws + (1u << 22));        // 4 MB
    bf16_t* part = (bf16_t*)(ws + (1u << 23));        // 4 * 4 MB = 16 MB

    conv_A<<<1024, 256, 0, stream>>>(A, dA, Ab);
    conv_B<<<1024, 256, 0, stream>>>(B, Bb);
    gemm1<<<dim3(128, 2, S_SPLIT), 256, 0, stream>>>(x, Ab, part);
    reduce_t<<<1024, 256, 0, stream>>>(part, tt);
    gemm2<<<dim3(64, 32), 256, 0, stream>>>(tt, Bb, dB, out);
}

// Round 2
// 319.667 us; speedup vs baseline: 1.0279x; 1.0279x over previous
//
#include <hip/hip_runtime.h>
#include <hip/hip_bf16.h>

// VeRA: out = SCALE * d_B[o] * ((x @ (d_A*A)^T) @ B^T)
// GEMM1 (split-K=4): part[s] = x @ Ab^T over K-chunk  (M=8192,N=256,K=1024 each)
// reduce: t = bf16(sum_s part[s])
// GEMM2: out = SCALE*d_B * (t @ Bb^T)  (M=8192,N=4096,K=256)
//
// R2: keep T2 swizzle + 2-phase dbuf. Restore gemm2 occupancy (48 KB LDS,
// 3 blocks/CU, grid 4096). Swapped-operand MFMA epilogue in both GEMMs ->
// per-thread col-runs -> float4 / bf16x4 stores. Fused conv kernel.

#define SCALE_F 0.125f
#define M_TOT 8192
#define K_IN 4096
#define RANK 256
#define N_OUT 4096
#define S_SPLIT 4
#define KC 1024   // K_IN / S_SPLIT

typedef __bf16 bf16_t;
typedef __bf16 bf16x8 __attribute__((ext_vector_type(8)));
typedef __bf16 bf16x4 __attribute__((ext_vector_type(4)));
typedef float f32x4 __attribute__((ext_vector_type(4)));

typedef __attribute__((address_space(3))) unsigned int lds_u32_t;
typedef const __attribute__((address_space(1))) unsigned int glob_u32_t;

__device__ __forceinline__ void async16(const void* g, void* l) {
    __builtin_amdgcn_global_load_lds((glob_u32_t*)g, (lds_u32_t*)l, 16, 0, 0);
}

// ---- convert A (fold d_A) and B to bf16, fused into one dispatch ----
// blocks [0,1024): A (4096x256 f32, scale rows by dA); [1024,2048): B.
__global__ __launch_bounds__(256) void conv_AB(const float* __restrict__ A,
                                               const float* __restrict__ dA,
                                               const float* __restrict__ B,
                                               bf16_t* __restrict__ Ab,
                                               bf16_t* __restrict__ Bb) {
    int b = blockIdx.x;
    if (b < 1024) {
        int idx = b * 256 + threadIdx.x;
        float4 v = ((const float4*)A)[idx];
        float s = dA[idx >> 10];
        bf16x4 o;
        o.x = (bf16_t)(v.x * s); o.y = (bf16_t)(v.y * s);
        o.z = (bf16_t)(v.z * s); o.w = (bf16_t)(v.w * s);
        ((bf16x4*)Ab)[idx] = o;
    } else {
        int idx = (b - 1024) * 256 + threadIdx.x;
        float4 v = ((const float4*)B)[idx];
        bf16x4 o;
        o.x = (bf16_t)v.x; o.y = (bf16_t)v.y;
        o.z = (bf16_t)v.z; o.w = (bf16_t)v.w;
        ((bf16x4*)Bb)[idx] = o;
    }
}

// ---- GEMM1: part[z][8192][256] = x(fp32) @ Ab^T over K-chunk z ----
// BM=64, BN=128, BK=64. grid (128, 2, 4). 4 waves 2x2, wave tile 32x64.
// sA via async16 (linear LDS dest, pre-swizzled global source); sX reg-staged
// f32->bf16, ds_write to swizzled slot. 48 KB LDS -> 3 blocks/CU.
// MFMA called with swapped operands -> thread holds col-runs -> bf16x4 stores.
__global__ __launch_bounds__(256) void gemm1(const float* __restrict__ x,
                                             const bf16_t* __restrict__ Ab,
                                             bf16_t* __restrict__ part) {
    __shared__ bf16_t sX[2][64 * 64];    // 8 KB per buffer
    __shared__ bf16_t sA[2][128 * 64];   // 16 KB per buffer
    const int tid = threadIdx.x;
    const int lane = tid & 63, wave = tid >> 6;
    const int wm = wave >> 1, wn = wave & 1;
    const int l15 = lane & 15, quad = lane >> 4;
    const int bm = blockIdx.x * 64;
    const int bn = blockIdx.y * 128;
    const int k0 = blockIdx.z * KC;

    f32x4 acc[2][4];   // [m-frag][n-frag], fragment holds 4 consecutive n
    const f32x4 zero = {0.f, 0.f, 0.f, 0.f};
    #pragma unroll
    for (int i = 0; i < 2; i++)
        #pragma unroll
        for (int j = 0; j < 4; j++) acc[i][j] = zero;

    f32x4 xr[2][2];   // in-flight x tile

    auto issue_x = [&](int kk) {
        #pragma unroll
        for (int c = 0; c < 2; c++) {
            int idx = c * 256 + tid;
            int row = idx >> 3, sl = idx & 7;
            const float* sp = &x[(size_t)(bm + row) * K_IN + kk + sl * 8];
            xr[c][0] = *(const f32x4*)sp;
            xr[c][1] = *(const f32x4*)(sp + 4);
        }
    };
    auto stage_a = [&](int b, int kk) {
        #pragma unroll
        for (int c = 0; c < 4; c++) {
            int idx = c * 256 + tid;
            int row = idx >> 3, sl = idx & 7;
            async16(&Ab[(size_t)(bn + row) * K_IN + kk + ((sl ^ (row & 7)) << 3)],
                    &sA[b][idx * 8]);
        }
    };
    auto write_x = [&](int b) {
        #pragma unroll
        for (int c = 0; c < 2; c++) {
            int idx = c * 256 + tid;
            int row = idx >> 3, sl = idx & 7;
            bf16x8 o;
            #pragma unroll
            for (int e = 0; e < 4; e++) {
                o[e]     = (bf16_t)xr[c][0][e];
                o[e + 4] = (bf16_t)xr[c][1][e];
            }
            *(bf16x8*)&sX[b][row * 64 + ((sl ^ (row & 7)) << 3)] = o;
        }
    };
    auto compute = [&](int b) {
        #pragma unroll
        for (int ks = 0; ks < 2; ks++) {
            bf16x8 af[2], bfr[4];
            #pragma unroll
            for (int i = 0; i < 2; i++) {
                int row = wm * 32 + i * 16 + l15;
                af[i] = *(const bf16x8*)&sX[b][row * 64 + ((((ks << 2) | quad) ^ (row & 7)) << 3)];
            }
            #pragma unroll
            for (int j = 0; j < 4; j++) {
                int row = wn * 64 + j * 16 + l15;
                bfr[j] = *(const bf16x8*)&sA[b][row * 64 + ((((ks << 2) | quad) ^ (row & 7)) << 3)];
            }
            // swapped operands: D^T fragment -> lane&15 = m, quad*4+r = n
            #pragma unroll
            for (int i = 0; i < 2; i++)
                #pragma unroll
                for (int j = 0; j < 4; j++)
                    acc[i][j] = __builtin_amdgcn_mfma_f32_16x16x32_bf16(bfr[j], af[i], acc[i][j], 0, 0, 0);
        }
    };

    issue_x(k0);
    stage_a(0, k0);
    write_x(0);
    __syncthreads();

    int cur = 0;
    for (int it = 1; it < KC / 64; ++it) {
        const int nxt = cur ^ 1;
        const int kk = k0 + it * 64;
        issue_x(kk);
        stage_a(nxt, kk);
        compute(cur);
        write_x(nxt);
        __syncthreads();
        cur = nxt;
    }
    compute(cur);

    bf16_t* p = part + (size_t)blockIdx.z * (M_TOT * RANK);
    #pragma unroll
    for (int i = 0; i < 2; i++) {
        int row = bm + wm * 32 + i * 16 + l15;
        #pragma unroll
        for (int j = 0; j < 4; j++) {
            int col = bn + wn * 64 + j * 16 + quad * 4;
            bf16x4 o;
            #pragma unroll
            for (int r = 0; r < 4; r++) o[r] = (bf16_t)acc[i][j][r];
            *(bf16x4*)&p[(size_t)row * RANK + col] = o;
        }
    }
}

// ---- reduce: t = bf16(sum_z part[z]) ----
__global__ __launch_bounds__(256) void reduce_t(const bf16_t* __restrict__ part,
                                                bf16_t* __restrict__ t) {
    int i = (blockIdx.x * 256 + threadIdx.x) * 8;
    float s[8] = {0.f, 0.f, 0.f, 0.f, 0.f, 0.f, 0.f, 0.f};
    #pragma unroll
    for (int z = 0; z < S_SPLIT; z++) {
        bf16x8 v = *(const bf16x8*)&part[(size_t)z * M_TOT * RANK + i];
        #pragma unroll
        for (int e = 0; e < 8; e++) s[e] += (float)v[e];
    }
    bf16x8 o;
    #pragma unroll
    for (int e = 0; e < 8; e++) o[e] = (bf16_t)s[e];
    *(bf16x8*)&t[i] = o;
}

// ---- GEMM2: out[8192][4096] = SCALE*dB * (t @ Bb^T) ----
// BM=128, BN=64, BK=64 (4 steps). grid (64,64)=4096 blocks. 4 waves 2x2,
// wave tile 64x32. Swizzle + 2-phase dbuf; 48 KB LDS -> 3 blocks/CU.
// Swapped-operand MFMA -> per-thread 4-col runs -> float4 stores.
__global__ __launch_bounds__(256) void gemm2(const bf16_t* __restrict__ t,
                                             const bf16_t* __restrict__ Bb,
                                             const float* __restrict__ dB,
                                             float* __restrict__ out) {
    __shared__ bf16_t sT[2][128 * 64];   // 16 KB each
    __shared__ bf16_t sB[2][64 * 64];    // 8 KB each
    const int tid = threadIdx.x;
    const int lane = tid & 63, wave = tid >> 6;
    const int wm = wave >> 1, wn = wave & 1;
    const int l15 = lane & 15, quad = lane >> 4;
    const int bm = blockIdx.x * 128;
    const int bn = blockIdx.y * 64;

    f32x4 acc[4][2];   // [m-frag][n-frag], fragment holds 4 consecutive n
    const f32x4 zero = {0.f, 0.f, 0.f, 0.f};
    #pragma unroll
    for (int i = 0; i < 4; i++)
        #pragma unroll
        for (int j = 0; j < 2; j++) acc[i][j] = zero;

    auto stage = [&](int b, int kt) {
        #pragma unroll
        for (int c = 0; c < 4; c++) {
            int idx = c * 256 + tid;
            int row = idx >> 3, sl = idx & 7;
            async16(&t[(size_t)(bm + row) * RANK + kt + ((sl ^ (row & 7)) << 3)],
                    &sT[b][idx * 8]);
        }
        #pragma unroll
        for (int c = 0; c < 2; c++) {
            int idx = c * 256 + tid;
            int row = idx >> 3, sl = idx & 7;
            async16(&Bb[(size_t)(bn + row) * RANK + kt + ((sl ^ (row & 7)) << 3)],
                    &sB[b][idx * 8]);
        }
    };
    auto compute = [&](int b) {
        #pragma unroll
        for (int ks = 0; ks < 2; ks++) {
            bf16x8 af[4], bfr[2];
            #pragma unroll
            for (int i = 0; i < 4; i++) {
                int row = wm * 64 + i * 16 + l15;
                af[i] = *(const bf16x8*)&sT[b][row * 64 + ((((ks << 2) | quad) ^ (row & 7)) << 3)];
            }
            #pragma unroll
            for (int j = 0; j < 2; j++) {
                int row = wn * 32 + j * 16 + l15;
                bfr[j] = *(const bf16x8*)&sB[b][row * 64 + ((((ks << 2) | quad) ^ (row & 7)) << 3)];
            }
            #pragma unroll
            for (int i = 0; i < 4; i++)
                #pragma unroll
                for (int j = 0; j < 2; j++)
                    acc[i][j] = __builtin_amdgcn_mfma_f32_16x16x32_bf16(bfr[j], af[i], acc[i][j], 0, 0, 0);
        }
    };

    stage(0, 0);
    __syncthreads();
    int cur = 0;
    #pragma unroll
    for (int it = 1; it < RANK / 64; ++it) {
        stage(cur ^ 1, it * 64);
        compute(cur);
        __syncthreads();
        cur ^= 1;
    }
    compute(cur);

    #pragma unroll
    for (int i = 0; i < 4; i++) {
        int row = bm + wm * 64 + i * 16 + l15;
        #pragma unroll
        for (int j = 0; j < 2; j++) {
            int col = bn + wn * 32 + j * 16 + quad * 4;
            f32x4 db = *(const f32x4*)&dB[col];
            f32x4 o;
            #pragma unroll
            for (int r = 0; r < 4; r++) o[r] = db[r] * SCALE_F * acc[i][j][r];
            *(f32x4*)&out[(size_t)row * N_OUT + col] = o;
        }
    }
}

extern "C" void kernel_launch(void* const* d_in, const int* in_sizes, int n_in,
                              void* d_out, int out_size, void* d_ws, size_t ws_size,
                              hipStream_t stream) {
    const float* x  = (const float*)d_in[0];
    const float* A  = (const float*)d_in[1];
    const float* B  = (const float*)d_in[2];
    const float* dA = (const float*)d_in[3];
    const float* dB = (const float*)d_in[4];
    float* out = (float*)d_out;

    char* ws = (char*)d_ws;
    bf16_t* Ab   = (bf16_t*)ws;                       // 2 MB
    bf16_t* Bb   = (bf16_t*)(ws + (1u << 21));        // 2 MB
    bf16_t* tt   = (bf16_t*)(ws + (1u << 22));        // 4 MB
    bf16_t* part = (bf16_t*)(ws + (1u << 23));        // 4 * 4 MB = 16 MB

    conv_AB<<<2048, 256, 0, stream>>>(A, dA, B, Ab, Bb);
    gemm1<<<dim3(128, 2, S_SPLIT), 256, 0, stream>>>(x, Ab, part);
    reduce_t<<<1024, 256, 0, stream>>>(part, tt);
    gemm2<<<dim3(64, 64), 256, 0, stream>>>(tt, Bb, dB, out);
}